// Round 18
// baseline (10480.642 us; speedup 1.0000x reference)
//
#include <hip/hip_runtime.h>
#include <math.h>

#define IQ     64
#define C_CH   256
#define T_SEQ  1024
#define NSTEP  (IQ * T_SEQ)
#define BLK    16   // steps per Picard block (= MFMA rows)

typedef _Float16 h8v __attribute__((ext_vector_type(8)));
typedef _Float16 h4v __attribute__((ext_vector_type(4)));
typedef float    f4v __attribute__((ext_vector_type(4)));

// 6-op tanh (round-14 verified): 1 - 2*rcp(1+e^{2x}), RTE f16 cast.
static __device__ __forceinline__ _Float16 tanh16(float x) {
    const float e = __expf(2.f * x);
    return (_Float16)fmaf(-2.f, __frcp_rn(1.f + e), 1.f);
}

// ---------------------------------------------------------------------------
// GEMM in [iq][c][t] layout (unchanged):
//   Out[iq][c][t] = act( sum_j A[c][j] * In[iq][j][t] (+ bias[c]) )
// ---------------------------------------------------------------------------
template <bool SIG>
__global__ void __launch_bounds__(256) gemm_ct(const float* __restrict__ A,
                                               const float* __restrict__ In,
                                               const float* __restrict__ bias,
                                               float* __restrict__ Out) {
    __shared__ float aT[64][65];
    __shared__ float bI[64][68];

    const int tid = threadIdx.x;
    const int t0  = blockIdx.x * 64;
    const int c0  = blockIdx.y * 64;
    const int iq  = blockIdx.z;

    const int tt = tid & 15;
    const int cc = tid >> 4;
    const int lr = tid >> 2;
    const int lq = tid & 3;

    float acc[4][4];
#pragma unroll
    for (int m = 0; m < 4; ++m)
#pragma unroll
        for (int n = 0; n < 4; ++n) acc[m][n] = 0.f;

    for (int kc = 0; kc < 4; ++kc) {
        const float* Ar = A + (size_t)(c0 + lr) * 256 + kc * 64;
#pragma unroll
        for (int k2 = 0; k2 < 4; ++k2) {
            float4 v = *(const float4*)(Ar + lq * 4 + k2 * 16);
            int jj = lq * 4 + k2 * 16;
            aT[jj + 0][lr] = v.x;
            aT[jj + 1][lr] = v.y;
            aT[jj + 2][lr] = v.z;
            aT[jj + 3][lr] = v.w;
        }
        const float* Ir = In + ((size_t)iq * 256 + kc * 64 + lr) * 1024 + t0;
#pragma unroll
        for (int k2 = 0; k2 < 4; ++k2) {
            float4 v = *(const float4*)(Ir + lq * 4 + k2 * 16);
            *(float4*)&bI[lr][lq * 4 + k2 * 16] = v;
        }
        __syncthreads();

#pragma unroll 8
        for (int jj = 0; jj < 64; ++jj) {
            const float a0 = aT[jj][cc * 4 + 0];
            const float a1 = aT[jj][cc * 4 + 1];
            const float a2 = aT[jj][cc * 4 + 2];
            const float a3 = aT[jj][cc * 4 + 3];
            const float4 b4 = *(const float4*)&bI[jj][tt * 4];
            acc[0][0] = fmaf(a0, b4.x, acc[0][0]);
            acc[0][1] = fmaf(a0, b4.y, acc[0][1]);
            acc[0][2] = fmaf(a0, b4.z, acc[0][2]);
            acc[0][3] = fmaf(a0, b4.w, acc[0][3]);
            acc[1][0] = fmaf(a1, b4.x, acc[1][0]);
            acc[1][1] = fmaf(a1, b4.y, acc[1][1]);
            acc[1][2] = fmaf(a1, b4.z, acc[1][2]);
            acc[1][3] = fmaf(a1, b4.w, acc[1][3]);
            acc[2][0] = fmaf(a2, b4.x, acc[2][0]);
            acc[2][1] = fmaf(a2, b4.y, acc[2][1]);
            acc[2][2] = fmaf(a2, b4.z, acc[2][2]);
            acc[2][3] = fmaf(a2, b4.w, acc[2][3]);
            acc[3][0] = fmaf(a3, b4.x, acc[3][0]);
            acc[3][1] = fmaf(a3, b4.y, acc[3][1]);
            acc[3][2] = fmaf(a3, b4.z, acc[3][2]);
            acc[3][3] = fmaf(a3, b4.w, acc[3][3]);
        }
        __syncthreads();
    }

#pragma unroll
    for (int m = 0; m < 4; ++m) {
        const int c = c0 + cc * 4 + m;
        float4 v;
        if constexpr (SIG) {
            const float bb = bias[c];
            v.x = __fdividef(1.f, 1.f + __expf(-(acc[m][0] + bb)));
            v.y = __fdividef(1.f, 1.f + __expf(-(acc[m][1] + bb)));
            v.z = __fdividef(1.f, 1.f + __expf(-(acc[m][2] + bb)));
            v.w = __fdividef(1.f, 1.f + __expf(-(acc[m][3] + bb)));
        } else {
            v.x = acc[m][0];
            v.y = acc[m][1];
            v.z = acc[m][2];
            v.w = acc[m][3];
        }
        *(float4*)(Out + ((size_t)iq * 256 + c) * 1024 + t0 + tt * 4) = v;
    }
}

// ---------------------------------------------------------------------------
// Block-Picard scan, round 18: round-17 numerics EXACTLY (MITER=2, absmax
// must stay 0.015625) with the commit PHASE eliminated -> 2 phases/block:
//   - iter2's g=3 lanes append row-0 writes: tanh(x15) into BOTH buffers
//     (R17's commit values), under iter2's existing lgkm+barrier.
//   - xprev update via __shfl from lanes 48+q (register-only, no barrier;
//     verified correct in round 16).
//   - global X-stores issued in the loop body after iter2's barrier
//     (fire-and-forget, overlap next block's iter1).
//   - xpb LDS buffer deleted.
// Unlike the failed R12/R13 fusion, phases contain NO global stores, NO
// xpb roundtrip, NO pre-MFMA divergent writes.
// ---------------------------------------------------------------------------
__global__ void __launch_bounds__(512, 1) scan_picard(const float* __restrict__ W,
                                                      const float* __restrict__ Up,
                                                      const float* __restrict__ dtp,
                                                      float* __restrict__ Xout) {
    // tx layout: byte = s*512 + (((c>>3) ^ s) & 31)*16 + (c&7)*2  (slot^row swizzle)
    __shared__ __align__(16) _Float16 tx0[BLK * C_CH];
    __shared__ __align__(16) _Float16 tx1[BLK * C_CH];

    const int tid  = threadIdx.x;
    const int lane = tid & 63;
    const int wv   = tid >> 6;        // 0..7
    const int g    = lane >> 4;       // 0..3
    const int q    = lane & 15;       // 0..15
    const int cb   = wv << 5;         // wave channel base (32 channels)
    const int ch0  = cb + q;          // j-tile 0 channel
    const int ch1  = cb + 16 + q;     // j-tile 1 channel
    const float dt = *dtp;
    const float a  = 1.f - dt;

    // B fragments + A-read offsets, rotated: logical i -> physical (wv+i)&7.
    auto ld8 = [](const float* p) -> h8v {
        float4 x = *(const float4*)p;
        float4 y = *(const float4*)(p + 4);
        h8v r;
        r[0] = (_Float16)x.x; r[1] = (_Float16)x.y;
        r[2] = (_Float16)x.z; r[3] = (_Float16)x.w;
        r[4] = (_Float16)y.x; r[5] = (_Float16)y.y;
        r[6] = (_Float16)y.z; r[7] = (_Float16)y.w;
        return r;
    };
    h8v wB0[8], wB1[8];
    int aoff[8];
#pragma unroll
    for (int i = 0; i < 8; ++i) {
        const int ktp = (wv + i) & 7;   // physical k-tile
        aoff[i] = q * 512 + (((4 * ktp + g) ^ q) * 16);
        wB0[i] = ld8(W + (size_t)ch0 * 256 + ktp * 32 + g * 8);
        wB1[i] = ld8(W + (size_t)ch1 * 256 + ktp * 32 + g * 8);
    }

    // Static per-lane constants for the L-MFMA.
    //   A-frag: A[i=q][k=4g+f] = L[q][4g+f] = (q>=4g+f) ? a^(q-4g-f) : 0
    //   C-in coefficients: aC[reg] = a^(4g+reg+1)
    h4v Lf;
    float aC[4];
    {
        const float l2a = log2f(a);
#pragma unroll
        for (int f = 0; f < 4; ++f) {
            const int e = q - (4 * g + f);
            Lf[f] = (e >= 0) ? (_Float16)exp2f((float)e * l2a) : (_Float16)0.f;
        }
        const float a2 = a * a, a4 = a2 * a2;
        const float ag = (g == 0) ? 1.f : (g == 1) ? a4 : (g == 2) ? a4 * a4 : a4 * a4 * a4;
        aC[0] = ag * a;
        aC[1] = ag * a2;
        aC[2] = ag * a2 * a;
        aC[3] = ag * a4;
    }

    int toff0[4], toff1[4];  // tanh scatter: row r = 4g+i+1 of ch0 / ch1
#pragma unroll
    for (int i = 0; i < 4; ++i) {
        const int r = 4 * g + i + 1;   // r==16 (g==3,i==3) guarded at use
        toff0[i] = r * 512 + ((((ch0 >> 3) ^ r) & 31) * 16) + (ch0 & 7) * 2;
        toff1[i] = r * 512 + ((((ch1 >> 3) ^ r) & 31) * 16) + (ch1 & 7) * 2;
    }

    {   // zero tx buffers (tanh(0)=0; row 0 of both = tanh(x_start)=0)
        h8v z = {};
        *(h8v*)&tx0[tid * 8] = z;
        *(h8v*)&tx1[tid * 8] = z;
    }
    __syncthreads();

    float xq0 = 0.f, xq1 = 0.f;   // xprev of ch0/ch1 (same across g-copies)
    f4v   Xc0, Xc1;               // final-iteration X (C-layout)
    float du0[4], du1[4];         // dt*u for this block, C-layout
    float4 un0, un1;              // u prefetch

    auto loadu = [&](int s, float4& o0, float4& o1) {
        const size_t base = ((size_t)(s >> 10) << 8);
        o0 = *(const float4*)(Up + (base + ch0) * 1024 + (s & 1023) + 4 * g);
        o1 = *(const float4*)(Up + (base + ch1) * 1024 + (s & 1023) + 4 * g);
    };

    loadu(0, un0, un1);
    du0[0] = dt * un0.x; du0[1] = dt * un0.y; du0[2] = dt * un0.z; du0[3] = dt * un0.w;
    du1[0] = dt * un1.x; du1[1] = dt * un1.y; du1[2] = dt * un1.z; du1[3] = dt * un1.w;

    // ---- one Picard iteration; wr0: also write row-0 = tanh(x15) to BOTH
    //      buffers from g=3 lanes (the fused commit, R17 values) ----
    auto iter = [&](const _Float16* txr, _Float16* txw, int wr0) {
        h8v A[8];
#pragma unroll
        for (int i = 0; i < 8; ++i)
            A[i] = *(const h8v*)((const char*)txr + aoff[i]);
        f4v c0e = {0.f, 0.f, 0.f, 0.f};
        f4v c0o = c0e, c1e = c0e, c1o = c0e;
        c0e = __builtin_amdgcn_mfma_f32_16x16x32_f16(A[0], wB0[0], c0e, 0, 0, 0);
        c1e = __builtin_amdgcn_mfma_f32_16x16x32_f16(A[0], wB1[0], c1e, 0, 0, 0);
        c0o = __builtin_amdgcn_mfma_f32_16x16x32_f16(A[1], wB0[1], c0o, 0, 0, 0);
        c1o = __builtin_amdgcn_mfma_f32_16x16x32_f16(A[1], wB1[1], c1o, 0, 0, 0);
        c0e = __builtin_amdgcn_mfma_f32_16x16x32_f16(A[2], wB0[2], c0e, 0, 0, 0);
        c1e = __builtin_amdgcn_mfma_f32_16x16x32_f16(A[2], wB1[2], c1e, 0, 0, 0);
        c0o = __builtin_amdgcn_mfma_f32_16x16x32_f16(A[3], wB0[3], c0o, 0, 0, 0);
        c1o = __builtin_amdgcn_mfma_f32_16x16x32_f16(A[3], wB1[3], c1o, 0, 0, 0);
        c0e = __builtin_amdgcn_mfma_f32_16x16x32_f16(A[4], wB0[4], c0e, 0, 0, 0);
        c1e = __builtin_amdgcn_mfma_f32_16x16x32_f16(A[4], wB1[4], c1e, 0, 0, 0);
        c0o = __builtin_amdgcn_mfma_f32_16x16x32_f16(A[5], wB0[5], c0o, 0, 0, 0);
        c1o = __builtin_amdgcn_mfma_f32_16x16x32_f16(A[5], wB1[5], c1o, 0, 0, 0);
        c0e = __builtin_amdgcn_mfma_f32_16x16x32_f16(A[6], wB0[6], c0e, 0, 0, 0);
        c1e = __builtin_amdgcn_mfma_f32_16x16x32_f16(A[6], wB1[6], c1e, 0, 0, 0);
        c0o = __builtin_amdgcn_mfma_f32_16x16x32_f16(A[7], wB0[7], c0o, 0, 0, 0);
        c1o = __builtin_amdgcn_mfma_f32_16x16x32_f16(A[7], wB1[7], c1o, 0, 0, 0);
        const f4v Y0 = c0e + c0o;   // y[steps 4g+reg][ch0]
        const f4v Y1 = c1e + c1o;   // y[steps 4g+reg][ch1]

        // R = dt*Y + du -> f16 via RTE casts
        h4v rB0, rB1;
#pragma unroll
        for (int i = 0; i < 4; ++i) {
            rB0[i] = (_Float16)fmaf(dt, Y0[i], du0[i]);
            rB1[i] = (_Float16)fmaf(dt, Y1[i], du1[i]);
        }
        // C-in = a^{step+1} * xprev
        f4v ci0, ci1;
#pragma unroll
        for (int i = 0; i < 4; ++i) {
            ci0[i] = aC[i] * xq0;
            ci1[i] = aC[i] * xq1;
        }
        const f4v X0 = __builtin_amdgcn_mfma_f32_16x16x16f16(Lf, rB0, ci0, 0, 0, 0);
        const f4v X1 = __builtin_amdgcn_mfma_f32_16x16x16f16(Lf, rB1, ci1, 0, 0, 0);
        Xc0 = X0;
        Xc1 = X1;

        // tanh -> tx rows 4g+i+1 (row 16 skipped)
#pragma unroll
        for (int i = 0; i < 4; ++i) {
            const _Float16 t0 = tanh16(X0[i]);
            const _Float16 t1 = tanh16(X1[i]);
            if (i < 3 || g < 3) {
                *(_Float16*)((char*)txw + toff0[i]) = t0;
                *(_Float16*)((char*)txw + toff1[i]) = t1;
            }
        }
        if (wr0 && g == 3) {
            // fused commit: row 0 (swizzle identity) of BOTH buffers =
            // tanh(x15); compiler CSEs with the discarded i==3 tanh above.
            const _Float16 t0 = tanh16(X0[3]);
            const _Float16 t1 = tanh16(X1[3]);
            tx0[ch0] = t0; tx1[ch0] = t0;
            tx0[ch1] = t1; tx1[ch1] = t1;
        }
        asm volatile("s_waitcnt lgkmcnt(0)" ::: "memory");
        __builtin_amdgcn_s_barrier();
        __builtin_amdgcn_sched_barrier(0);
    };

    // One block per loop: 2 fused phases, no commit phase.
#pragma unroll 1
    for (int it = 0; it < NSTEP / BLK; ++it) {
        const int s0 = it * BLK;

        loadu(s0 + BLK, un0, un1);     // prefetch next block's u
                                       // (last overrun lands in out1: unused)
        iter(tx0, tx1, 0);
        iter(tx1, tx0, 1);

        // fire-and-forget X-store (overlaps next block's iter1)
        {
            const size_t base = ((size_t)(s0 >> 10) << 8);
            float* p0 = Xout + (base + ch0) * 1024 + (s0 & 1023) + 4 * g;
            float* p1 = Xout + (base + ch1) * 1024 + (s0 & 1023) + 4 * g;
            *(float4*)p0 = make_float4(Xc0[0], Xc0[1], Xc0[2], Xc0[3]);
            *(float4*)p1 = make_float4(Xc1[0], Xc1[1], Xc1[2], Xc1[3]);
        }
        // xprev via register shuffle: x15 of channel cb+q is lane 48+q's X[3]
        xq0 = __shfl(Xc0[3], 48 + q, 64);
        xq1 = __shfl(Xc1[3], 48 + q, 64);
        du0[0] = dt * un0.x; du0[1] = dt * un0.y; du0[2] = dt * un0.z; du0[3] = dt * un0.w;
        du1[0] = dt * un1.x; du1[1] = dt * un1.y; du1[2] = dt * un1.z; du1[3] = dt * un1.w;
    }
}

// ---------------------------------------------------------------------------
extern "C" void kernel_launch(void* const* d_in, const int* in_sizes, int n_in,
                              void* d_out, int out_size, void* d_ws, size_t ws_size,
                              hipStream_t stream) {
    const float* u  = (const float*)d_in[0];
    const float* dt = (const float*)d_in[1];
    const float* W  = (const float*)d_in[2];
    const float* M  = (const float*)d_in[3];
    const float* H  = (const float*)d_in[4];
    const float* b  = (const float*)d_in[5];

    float* out0 = (float*)d_out;                        // outputs region (Y)
    float* out1 = out0 + (size_t)IQ * C_CH * T_SEQ;     // membrane region (X)

    dim3 ggrid(T_SEQ / 64, C_CH / 64, IQ);

    // 1) Uproj[iq][c][t] = M @ u_iq  -> staged in out0 (overwritten by Y later)
    gemm_ct<false><<<ggrid, 256, 0, stream>>>(M, u, nullptr, out0);

    // 2) Block-Picard scan over 65536 steps; membrane potentials -> out1
    scan_picard<<<1, 512, 0, stream>>>(W, out0, dt, out1);

    // 3) Y[iq][c][t] = sigmoid(H @ X_iq + b) -> out0
    gemm_ct<true><<<ggrid, 256, 0, stream>>>(H, out1, b, out0);
}

// Round 19
// 10143.422 us; speedup vs baseline: 1.0332x; 1.0332x over previous
//
#include <hip/hip_runtime.h>
#include <math.h>

#define IQ     64
#define C_CH   256
#define T_SEQ  1024
#define NSTEP  (IQ * T_SEQ)
#define BLK    16   // steps per Picard block (= MFMA rows)

typedef _Float16 h8v __attribute__((ext_vector_type(8)));
typedef _Float16 h4v __attribute__((ext_vector_type(4)));
typedef float    f4v __attribute__((ext_vector_type(4)));

// 6-op tanh (round-14 verified): 1 - 2*rcp(1+e^{2x}), RTE f16 cast.
static __device__ __forceinline__ _Float16 tanh16(float x) {
    const float e = __expf(2.f * x);
    return (_Float16)fmaf(-2.f, __frcp_rn(1.f + e), 1.f);
}

// ---------------------------------------------------------------------------
// GEMM in [iq][c][t] layout:
//   Out[iq][c][t] = act( sum_j A[c][j] * In[iq][j][t] (+ bias[c]) )
// ---------------------------------------------------------------------------
template <bool SIG>
__global__ void __launch_bounds__(256) gemm_ct(const float* __restrict__ A,
                                               const float* __restrict__ In,
                                               const float* __restrict__ bias,
                                               float* __restrict__ Out) {
    __shared__ float aT[64][65];
    __shared__ float bI[64][68];

    const int tid = threadIdx.x;
    const int t0  = blockIdx.x * 64;
    const int c0  = blockIdx.y * 64;
    const int iq  = blockIdx.z;

    const int tt = tid & 15;
    const int cc = tid >> 4;
    const int lr = tid >> 2;
    const int lq = tid & 3;

    float acc[4][4];
#pragma unroll
    for (int m = 0; m < 4; ++m)
#pragma unroll
        for (int n = 0; n < 4; ++n) acc[m][n] = 0.f;

    for (int kc = 0; kc < 4; ++kc) {
        const float* Ar = A + (size_t)(c0 + lr) * 256 + kc * 64;
#pragma unroll
        for (int k2 = 0; k2 < 4; ++k2) {
            float4 v = *(const float4*)(Ar + lq * 4 + k2 * 16);
            int jj = lq * 4 + k2 * 16;
            aT[jj + 0][lr] = v.x;
            aT[jj + 1][lr] = v.y;
            aT[jj + 2][lr] = v.z;
            aT[jj + 3][lr] = v.w;
        }
        const float* Ir = In + ((size_t)iq * 256 + kc * 64 + lr) * 1024 + t0;
#pragma unroll
        for (int k2 = 0; k2 < 4; ++k2) {
            float4 v = *(const float4*)(Ir + lq * 4 + k2 * 16);
            *(float4*)&bI[lr][lq * 4 + k2 * 16] = v;
        }
        __syncthreads();

#pragma unroll 8
        for (int jj = 0; jj < 64; ++jj) {
            const float a0 = aT[jj][cc * 4 + 0];
            const float a1 = aT[jj][cc * 4 + 1];
            const float a2 = aT[jj][cc * 4 + 2];
            const float a3 = aT[jj][cc * 4 + 3];
            const float4 b4 = *(const float4*)&bI[jj][tt * 4];
            acc[0][0] = fmaf(a0, b4.x, acc[0][0]);
            acc[0][1] = fmaf(a0, b4.y, acc[0][1]);
            acc[0][2] = fmaf(a0, b4.z, acc[0][2]);
            acc[0][3] = fmaf(a0, b4.w, acc[0][3]);
            acc[1][0] = fmaf(a1, b4.x, acc[1][0]);
            acc[1][1] = fmaf(a1, b4.y, acc[1][1]);
            acc[1][2] = fmaf(a1, b4.z, acc[1][2]);
            acc[1][3] = fmaf(a1, b4.w, acc[1][3]);
            acc[2][0] = fmaf(a2, b4.x, acc[2][0]);
            acc[2][1] = fmaf(a2, b4.y, acc[2][1]);
            acc[2][2] = fmaf(a2, b4.z, acc[2][2]);
            acc[2][3] = fmaf(a2, b4.w, acc[2][3]);
            acc[3][0] = fmaf(a3, b4.x, acc[3][0]);
            acc[3][1] = fmaf(a3, b4.y, acc[3][1]);
            acc[3][2] = fmaf(a3, b4.z, acc[3][2]);
            acc[3][3] = fmaf(a3, b4.w, acc[3][3]);
        }
        __syncthreads();
    }

#pragma unroll
    for (int m = 0; m < 4; ++m) {
        const int c = c0 + cc * 4 + m;
        float4 v;
        if constexpr (SIG) {
            const float bb = bias[c];
            v.x = __fdividef(1.f, 1.f + __expf(-(acc[m][0] + bb)));
            v.y = __fdividef(1.f, 1.f + __expf(-(acc[m][1] + bb)));
            v.z = __fdividef(1.f, 1.f + __expf(-(acc[m][2] + bb)));
            v.w = __fdividef(1.f, 1.f + __expf(-(acc[m][3] + bb)));
        } else {
            v.x = acc[m][0];
            v.y = acc[m][1];
            v.z = acc[m][2];
            v.w = acc[m][3];
        }
        *(float4*)(Out + ((size_t)iq * 256 + c) * 1024 + t0 + tt * 4) = v;
    }
}

// ---------------------------------------------------------------------------
// Block-Picard scan — FINAL (round-17 configuration, best measured 10.15 ms
// total). 8 waves x 32 channels, MITER=2, 3 phases/block (2 iters + commit),
// rotated k-tiles, slot^row XOR swizzle, rcp-tanh, RTE f16 casts, W-matvec
// and in-block recurrence both on MFMA (L = lower-tri Toeplitz of a=1-dt).
// Block time is pinned (~6,000 cyc) by aggregate LDS+MFMA+VALU throughput
// across lockstep waves — phase-count (R18), latency trims (R16), chain
// shape (R13) all neutral; MITER=2 is the accuracy limit (absmax 0.0156
// vs threshold 0.025; the bf16-ref floor is 0.0078).
// ---------------------------------------------------------------------------
__global__ void __launch_bounds__(512, 1) scan_picard(const float* __restrict__ W,
                                                      const float* __restrict__ Up,
                                                      const float* __restrict__ dtp,
                                                      float* __restrict__ Xout) {
    // tx layout: byte = s*512 + (((c>>3) ^ s) & 31)*16 + (c&7)*2  (slot^row swizzle)
    __shared__ __align__(16) _Float16 tx0[BLK * C_CH];
    __shared__ __align__(16) _Float16 tx1[BLK * C_CH];
    __shared__ __align__(16) float    xpb[C_CH];   // xprev broadcast

    const int tid  = threadIdx.x;
    const int lane = tid & 63;
    const int wv   = tid >> 6;        // 0..7
    const int g    = lane >> 4;       // 0..3
    const int q    = lane & 15;       // 0..15
    const int cb   = wv << 5;         // wave channel base (32 channels)
    const int ch0  = cb + q;          // j-tile 0 channel
    const int ch1  = cb + 16 + q;     // j-tile 1 channel
    const float dt = *dtp;
    const float a  = 1.f - dt;

    // B fragments + A-read offsets, rotated: logical i -> physical (wv+i)&7.
    auto ld8 = [](const float* p) -> h8v {
        float4 x = *(const float4*)p;
        float4 y = *(const float4*)(p + 4);
        h8v r;
        r[0] = (_Float16)x.x; r[1] = (_Float16)x.y;
        r[2] = (_Float16)x.z; r[3] = (_Float16)x.w;
        r[4] = (_Float16)y.x; r[5] = (_Float16)y.y;
        r[6] = (_Float16)y.z; r[7] = (_Float16)y.w;
        return r;
    };
    h8v wB0[8], wB1[8];
    int aoff[8];
#pragma unroll
    for (int i = 0; i < 8; ++i) {
        const int ktp = (wv + i) & 7;   // physical k-tile
        aoff[i] = q * 512 + (((4 * ktp + g) ^ q) * 16);
        wB0[i] = ld8(W + (size_t)ch0 * 256 + ktp * 32 + g * 8);
        wB1[i] = ld8(W + (size_t)ch1 * 256 + ktp * 32 + g * 8);
    }

    // Static per-lane constants for the L-MFMA.
    //   A-frag: A[i=q][k=4g+f] = L[q][4g+f] = (q>=4g+f) ? a^(q-4g-f) : 0
    //   C-in coefficients: aC[reg] = a^(4g+reg+1)
    h4v Lf;
    float aC[4];
    {
        const float l2a = log2f(a);
#pragma unroll
        for (int f = 0; f < 4; ++f) {
            const int e = q - (4 * g + f);
            Lf[f] = (e >= 0) ? (_Float16)exp2f((float)e * l2a) : (_Float16)0.f;
        }
        const float a2 = a * a, a4 = a2 * a2;
        const float ag = (g == 0) ? 1.f : (g == 1) ? a4 : (g == 2) ? a4 * a4 : a4 * a4 * a4;
        aC[0] = ag * a;
        aC[1] = ag * a2;
        aC[2] = ag * a2 * a;
        aC[3] = ag * a4;
    }

    int toff0[4], toff1[4];  // tanh scatter: row r = 4g+i+1 of ch0 / ch1
#pragma unroll
    for (int i = 0; i < 4; ++i) {
        const int r = 4 * g + i + 1;   // r==16 (g==3,i==3) guarded at use
        toff0[i] = r * 512 + ((((ch0 >> 3) ^ r) & 31) * 16) + (ch0 & 7) * 2;
        toff1[i] = r * 512 + ((((ch1 >> 3) ^ r) & 31) * 16) + (ch1 & 7) * 2;
    }

    {   // zero tx buffers (tanh(0)=0) and xprev broadcast buffer
        h8v z = {};
        *(h8v*)&tx0[tid * 8] = z;
        *(h8v*)&tx1[tid * 8] = z;
        if (tid < 256) xpb[tid] = 0.f;
    }
    __syncthreads();

    float xq0 = 0.f, xq1 = 0.f;   // xprev of ch0/ch1 (same across g-copies)
    f4v   Xc0, Xc1;               // final-iteration X (C-layout)
    float du0[4], du1[4];         // dt*u for this block, C-layout
    float4 un0, un1;              // u prefetch

    auto loadu = [&](int s, float4& o0, float4& o1) {
        const size_t base = ((size_t)(s >> 10) << 8);
        o0 = *(const float4*)(Up + (base + ch0) * 1024 + (s & 1023) + 4 * g);
        o1 = *(const float4*)(Up + (base + ch1) * 1024 + (s & 1023) + 4 * g);
    };

    loadu(0, un0, un1);
    du0[0] = dt * un0.x; du0[1] = dt * un0.y; du0[2] = dt * un0.z; du0[3] = dt * un0.w;
    du1[0] = dt * un1.x; du1[1] = dt * un1.y; du1[2] = dt * un1.z; du1[3] = dt * un1.w;

    // ---- one Picard iteration ----
    auto iter = [&](const _Float16* txr, _Float16* txw) {
        h8v A[8];
#pragma unroll
        for (int i = 0; i < 8; ++i)
            A[i] = *(const h8v*)((const char*)txr + aoff[i]);
        f4v c0e = {0.f, 0.f, 0.f, 0.f};
        f4v c0o = c0e, c1e = c0e, c1o = c0e;
        c0e = __builtin_amdgcn_mfma_f32_16x16x32_f16(A[0], wB0[0], c0e, 0, 0, 0);
        c1e = __builtin_amdgcn_mfma_f32_16x16x32_f16(A[0], wB1[0], c1e, 0, 0, 0);
        c0o = __builtin_amdgcn_mfma_f32_16x16x32_f16(A[1], wB0[1], c0o, 0, 0, 0);
        c1o = __builtin_amdgcn_mfma_f32_16x16x32_f16(A[1], wB1[1], c1o, 0, 0, 0);
        c0e = __builtin_amdgcn_mfma_f32_16x16x32_f16(A[2], wB0[2], c0e, 0, 0, 0);
        c1e = __builtin_amdgcn_mfma_f32_16x16x32_f16(A[2], wB1[2], c1e, 0, 0, 0);
        c0o = __builtin_amdgcn_mfma_f32_16x16x32_f16(A[3], wB0[3], c0o, 0, 0, 0);
        c1o = __builtin_amdgcn_mfma_f32_16x16x32_f16(A[3], wB1[3], c1o, 0, 0, 0);
        c0e = __builtin_amdgcn_mfma_f32_16x16x32_f16(A[4], wB0[4], c0e, 0, 0, 0);
        c1e = __builtin_amdgcn_mfma_f32_16x16x32_f16(A[4], wB1[4], c1e, 0, 0, 0);
        c0o = __builtin_amdgcn_mfma_f32_16x16x32_f16(A[5], wB0[5], c0o, 0, 0, 0);
        c1o = __builtin_amdgcn_mfma_f32_16x16x32_f16(A[5], wB1[5], c1o, 0, 0, 0);
        c0e = __builtin_amdgcn_mfma_f32_16x16x32_f16(A[6], wB0[6], c0e, 0, 0, 0);
        c1e = __builtin_amdgcn_mfma_f32_16x16x32_f16(A[6], wB1[6], c1e, 0, 0, 0);
        c0o = __builtin_amdgcn_mfma_f32_16x16x32_f16(A[7], wB0[7], c0o, 0, 0, 0);
        c1o = __builtin_amdgcn_mfma_f32_16x16x32_f16(A[7], wB1[7], c1o, 0, 0, 0);
        const f4v Y0 = c0e + c0o;   // y[steps 4g+reg][ch0]
        const f4v Y1 = c1e + c1o;   // y[steps 4g+reg][ch1]

        // R = dt*Y + du -> f16 via RTE casts
        h4v rB0, rB1;
#pragma unroll
        for (int i = 0; i < 4; ++i) {
            rB0[i] = (_Float16)fmaf(dt, Y0[i], du0[i]);
            rB1[i] = (_Float16)fmaf(dt, Y1[i], du1[i]);
        }
        // C-in = a^{step+1} * xprev
        f4v ci0, ci1;
#pragma unroll
        for (int i = 0; i < 4; ++i) {
            ci0[i] = aC[i] * xq0;
            ci1[i] = aC[i] * xq1;
        }
        const f4v X0 = __builtin_amdgcn_mfma_f32_16x16x16f16(Lf, rB0, ci0, 0, 0, 0);
        const f4v X1 = __builtin_amdgcn_mfma_f32_16x16x16f16(Lf, rB1, ci1, 0, 0, 0);
        Xc0 = X0;
        Xc1 = X1;

        // tanh -> tx rows 4g+i+1 (row 16 skipped; row 0 refreshed at commit)
#pragma unroll
        for (int i = 0; i < 4; ++i) {
            const _Float16 t0 = tanh16(X0[i]);
            const _Float16 t1 = tanh16(X1[i]);
            if (i < 3 || g < 3) {
                *(_Float16*)((char*)txw + toff0[i]) = t0;
                *(_Float16*)((char*)txw + toff1[i]) = t1;
            }
        }
        asm volatile("s_waitcnt lgkmcnt(0)" ::: "memory");
        __builtin_amdgcn_s_barrier();
        __builtin_amdgcn_sched_barrier(0);
    };

    // ---- commit: X -> global, row0 + xprev broadcast ----
    auto commit = [&](int s0) {
        const size_t base = ((size_t)(s0 >> 10) << 8);
        float* p0 = Xout + (base + ch0) * 1024 + (s0 & 1023) + 4 * g;
        float* p1 = Xout + (base + ch1) * 1024 + (s0 & 1023) + 4 * g;
        *(float4*)p0 = make_float4(Xc0[0], Xc0[1], Xc0[2], Xc0[3]);
        *(float4*)p1 = make_float4(Xc1[0], Xc1[1], Xc1[2], Xc1[3]);
        if (g == 3) {   // lanes holding step 15
            const _Float16 t0 = tanh16(Xc0[3]);
            const _Float16 t1 = tanh16(Xc1[3]);
            tx0[ch0] = t0; tx1[ch0] = t0;   // row-0 swizzle is identity
            tx0[ch1] = t1; tx1[ch1] = t1;
            xpb[ch0] = Xc0[3];
            xpb[ch1] = Xc1[3];
        }
        asm volatile("s_waitcnt lgkmcnt(0)" ::: "memory");  // intra-wave W->R
        xq0 = xpb[ch0];
        xq1 = xpb[ch1];
        asm volatile("s_waitcnt lgkmcnt(0)" ::: "memory");
        __builtin_amdgcn_s_barrier();
        __builtin_amdgcn_sched_barrier(0);
    };

    // One block per loop; 2 iters => parity returns to tx0 every block.
#pragma unroll 1
    for (int it = 0; it < NSTEP / BLK; ++it) {
        const int s0 = it * BLK;

        loadu(s0 + BLK, un0, un1);     // prefetch next block's u
                                       // (last overrun lands in out1: unused)
        iter(tx0, tx1);
        iter(tx1, tx0);
        commit(s0);
        du0[0] = dt * un0.x; du0[1] = dt * un0.y; du0[2] = dt * un0.z; du0[3] = dt * un0.w;
        du1[0] = dt * un1.x; du1[1] = dt * un1.y; du1[2] = dt * un1.z; du1[3] = dt * un1.w;
    }
}

// ---------------------------------------------------------------------------
extern "C" void kernel_launch(void* const* d_in, const int* in_sizes, int n_in,
                              void* d_out, int out_size, void* d_ws, size_t ws_size,
                              hipStream_t stream) {
    const float* u  = (const float*)d_in[0];
    const float* dt = (const float*)d_in[1];
    const float* W  = (const float*)d_in[2];
    const float* M  = (const float*)d_in[3];
    const float* H  = (const float*)d_in[4];
    const float* b  = (const float*)d_in[5];

    float* out0 = (float*)d_out;                        // outputs region (Y)
    float* out1 = out0 + (size_t)IQ * C_CH * T_SEQ;     // membrane region (X)

    dim3 ggrid(T_SEQ / 64, C_CH / 64, IQ);

    // 1) Uproj[iq][c][t] = M @ u_iq  -> staged in out0 (overwritten by Y later)
    gemm_ct<false><<<ggrid, 256, 0, stream>>>(M, u, nullptr, out0);

    // 2) Block-Picard scan over 65536 steps; membrane potentials -> out1
    scan_picard<<<1, 512, 0, stream>>>(W, out0, dt, out1);

    // 3) Y[iq][c][t] = sigmoid(H @ X_iq + b) -> out0
    gemm_ct<true><<<ggrid, 256, 0, stream>>>(H, out1, b, out0);
}